// Round 1
// baseline (514.073 us; speedup 1.0000x reference)
//
#include <hip/hip_runtime.h>
#include <stdint.h>

#define D_  1024
#define H_  16
#define DK_ 64
#define E_  4096
#define B_  2
#define S_  2048

typedef unsigned short u16;
typedef short bf16x8 __attribute__((ext_vector_type(8)));
typedef float f32x4 __attribute__((ext_vector_type(4)));

__device__ __forceinline__ u16 f2b(float f) {
  union { float f; unsigned u; } v; v.f = f;
  return (u16)((v.u + 0x7FFFu + ((v.u >> 16) & 1u)) >> 16);
}

__device__ __forceinline__ void gload16(const void* g, void* l) {
  __builtin_amdgcn_global_load_lds(
      (const __attribute__((address_space(1))) unsigned*)g,
      (__attribute__((address_space(3))) unsigned*)l, 16, 0, 0);
}

__device__ __forceinline__ f32x4 mfma16(bf16x8 a, bf16x8 b, f32x4 c) {
  return __builtin_amdgcn_mfma_f32_16x16x32_bf16(a, b, c, 0, 0, 0);
}

// ---------------- convert f32 -> bf16 (vectorized) ----------------
__global__ __launch_bounds__(256) void convert_f32_bf16(
    const float* __restrict__ in, u16* __restrict__ out, int n) {
  int i = (blockIdx.x * 256 + threadIdx.x) * 4;
  if (i >= n) return;
  float4 v = *reinterpret_cast<const float4*>(in + i);
  union { u16 h[4]; uint2 u; } o;
  o.h[0] = f2b(v.x); o.h[1] = f2b(v.y); o.h[2] = f2b(v.z); o.h[3] = f2b(v.w);
  *reinterpret_cast<uint2*>(out + i) = o.u;
}

// ---------------- batched transpose (R x C f32) -> (C x R bf16) ----------------
__global__ __launch_bounds__(256) void transpose_f32_bf16(
    const float* __restrict__ src, u16* __restrict__ dst,
    int R, int C, long long src_bs, long long dst_bs) {
  __shared__ float tile[32][33];
  const float* s = src + blockIdx.z * src_bs;
  u16* d = dst + blockIdx.z * dst_bs;
  int c0 = blockIdx.x * 32, r0 = blockIdx.y * 32;
  int tx = threadIdx.x, ty = threadIdx.y;   // (32, 8)
  #pragma unroll
  for (int i = 0; i < 4; i++)
    tile[ty + 8*i][tx] = s[(size_t)(r0 + ty + 8*i) * C + c0 + tx];
  __syncthreads();
  #pragma unroll
  for (int i = 0; i < 4; i++)
    d[(size_t)(c0 + ty + 8*i) * R + r0 + tx] = f2b(tile[tx][ty + 8*i]);
}

// ---------------- GEMM: C = A(MxK) * BT(NxK)^T, m97 structure ----------------
// EPI 0: QKV scatter -> bf16 q/k/v [(b,h,s,dk)], outb = q base (k,v contiguous)
// EPI 1: outf[row*N+col] = acc + bias[col] + resid[row*N+col]   (fp32)
// EPI 2: outb[row*N+col] = bf16(relu(acc + bias[col]))
template<int EPI>
__global__ __launch_bounds__(256) void gemm_bt(
    const u16* __restrict__ A, const u16* __restrict__ BT,
    int M, int N, int K,
    float* __restrict__ outf, u16* __restrict__ outb,
    const float* __restrict__ bias, const float* __restrict__ resid) {
  __shared__ __align__(16) u16 As[128 * 32];
  __shared__ __align__(16) u16 Bs[128 * 32];
  int t = threadIdx.x;
  int lane = t & 63, w = t >> 6;
  int wr = w >> 1, wc = w & 1;
  int l15 = lane & 15, g = lane >> 4;
  int m0 = blockIdx.y * 128, n0 = blockIdx.x * 128;

  f32x4 acc[4][4] = {};

  const u16* Arow = A + (size_t)(m0 + (t >> 2)) * K + (t & 3) * 8;
  const u16* Brow = BT + (size_t)(n0 + (t >> 2)) * K + (t & 3) * 8;
  u16* AsDst = &As[t * 8];
  u16* BsDst = &Bs[t * 8];

  for (int k0 = 0; k0 < K; k0 += 32) {
    __syncthreads();                       // protect LDS from previous-iter reads
    gload16(Arow + k0,                 AsDst);
    gload16(Arow + k0 + (size_t)64*K,  AsDst + 64*32);
    gload16(Brow + k0,                 BsDst);
    gload16(Brow + k0 + (size_t)64*K,  BsDst + 64*32);
    __syncthreads();                       // drains vmcnt before reads

    bf16x8 af[4], bfr[4];
    #pragma unroll
    for (int i = 0; i < 4; i++)
      af[i] = *(const bf16x8*)&As[(wr*64 + i*16 + l15) * 32 + g*8];
    #pragma unroll
    for (int i = 0; i < 4; i++)
      bfr[i] = *(const bf16x8*)&Bs[(wc*64 + i*16 + l15) * 32 + g*8];
    #pragma unroll
    for (int mi = 0; mi < 4; mi++)
      #pragma unroll
      for (int ni = 0; ni < 4; ni++)
        acc[mi][ni] = mfma16(af[mi], bfr[ni], acc[mi][ni]);
  }

  #pragma unroll
  for (int mi = 0; mi < 4; mi++) {
    #pragma unroll
    for (int ni = 0; ni < 4; ni++) {
      int col = n0 + wc*64 + ni*16 + l15;
      #pragma unroll
      for (int j = 0; j < 4; j++) {
        int row = m0 + wr*64 + mi*16 + g*4 + j;
        float v = acc[mi][ni][j];
        if constexpr (EPI == 0) {
          int which = col >> 10, h = (col >> 6) & 15, kk = col & 63;
          int b = row >> 11, s = row & 2047;
          size_t dst = (size_t)which * (B_*H_*S_*DK_) +
                       (((size_t)(b * H_ + h)) * S_ + s) * DK_ + kk;
          outb[dst] = f2b(v);
        } else if constexpr (EPI == 1) {
          outf[(size_t)row * N + col] = v + bias[col] + resid[(size_t)row * N + col];
        } else {
          outb[(size_t)row * N + col] = f2b(fmaxf(v + bias[col], 0.0f));
        }
      }
    }
  }
}

// ---------------- flash attention (bf16 in, bf16 ctx out) ----------------
// grid: (S/64, B*H), 256 threads = 4 waves, each wave owns 16 q-rows
__global__ __launch_bounds__(256) void attn_kernel(
    const u16* __restrict__ q, const u16* __restrict__ k,
    const u16* __restrict__ v, u16* __restrict__ ctx) {
  __shared__ __align__(16) u16 p_lds[4][16][72];
  __shared__ __align__(16) u16 vt_lds[64][72];
  int t = threadIdx.x, lane = t & 63, w = t >> 6;
  int l15 = lane & 15, g = lane >> 4;
  int bh = blockIdx.y;
  int q0 = blockIdx.x * 64 + w * 16;
  const u16* qb = q + (size_t)bh * S_ * DK_;
  const u16* kb = k + (size_t)bh * S_ * DK_;
  const u16* vb = v + (size_t)bh * S_ * DK_;

  bf16x8 qf[2];
  qf[0] = *(const bf16x8*)&qb[(size_t)(q0 + l15) * DK_ + g*8];
  qf[1] = *(const bf16x8*)&qb[(size_t)(q0 + l15) * DK_ + 32 + g*8];

  f32x4 cacc[4] = {};
  float mold[4] = {-1e30f, -1e30f, -1e30f, -1e30f};
  float lsum[4] = {0.f, 0.f, 0.f, 0.f};

  for (int kb0 = 0; kb0 < S_; kb0 += 64) {
    __syncthreads();   // protect vt_lds/p_lds from previous-iter reads
    // stage V-tile transposed into LDS (padded: stride 72 -> no 16-way conflict)
    #pragma unroll
    for (int i = 0; i < 2; i++) {
      int sv = (t >> 3) + i * 32;
      int dk0 = (t & 7) * 8;
      bf16x8 vv = *(const bf16x8*)&vb[(size_t)(kb0 + sv) * DK_ + dk0];
      #pragma unroll
      for (int ii = 0; ii < 8; ii++) vt_lds[dk0 + ii][sv] = ((const u16*)&vv)[ii];
    }
    // scores: S = Q @ K^T  (K rows are the B^T operand, read direct from global)
    f32x4 sacc[4] = {};
    #pragma unroll
    for (int nt = 0; nt < 4; nt++) {
      #pragma unroll
      for (int kc = 0; kc < 2; kc++) {
        bf16x8 kf = *(const bf16x8*)&kb[(size_t)(kb0 + nt*16 + l15) * DK_ + kc*32 + g*8];
        sacc[nt] = mfma16(qf[kc], kf, sacc[nt]);
      }
    }
    #pragma unroll
    for (int nt = 0; nt < 4; nt++) sacc[nt] *= 0.125f;   // 1/sqrt(64)

    // online softmax; row r = g*4+j lives in 16 lanes (l15) x 4 accs
    float pj[4][4];
    #pragma unroll
    for (int j = 0; j < 4; j++) {
      float mx = fmaxf(fmaxf(sacc[0][j], sacc[1][j]), fmaxf(sacc[2][j], sacc[3][j]));
      #pragma unroll
      for (int off = 8; off; off >>= 1) mx = fmaxf(mx, __shfl_xor(mx, off, 16));
      float mnew = fmaxf(mold[j], mx);
      float corr = __expf(mold[j] - mnew);
      float ps = 0.f;
      #pragma unroll
      for (int nt = 0; nt < 4; nt++) {
        float p = __expf(sacc[nt][j] - mnew);
        pj[nt][j] = p; ps += p;
      }
      #pragma unroll
      for (int off = 8; off; off >>= 1) ps += __shfl_xor(ps, off, 16);
      lsum[j] = lsum[j] * corr + ps;
      mold[j] = mnew;
      #pragma unroll
      for (int dt = 0; dt < 4; dt++) cacc[dt][j] *= corr;
    }
    // P (D-layout) -> LDS -> A-layout
    #pragma unroll
    for (int nt = 0; nt < 4; nt++)
      #pragma unroll
      for (int j = 0; j < 4; j++)
        p_lds[w][g*4 + j][nt*16 + l15] = f2b(pj[nt][j]);
    __syncthreads();   // vt_lds staged by all waves + p_lds visible

    // ctx += P @ V
    #pragma unroll
    for (int kc = 0; kc < 2; kc++) {
      bf16x8 pa = *(const bf16x8*)&p_lds[w][l15][kc*32 + g*8];
      #pragma unroll
      for (int dt = 0; dt < 4; dt++) {
        bf16x8 vf = *(const bf16x8*)&vt_lds[dt*16 + l15][kc*32 + g*8];
        cacc[dt] = mfma16(pa, vf, cacc[dt]);
      }
    }
  }

  int b = bh >> 4, h = bh & 15;
  #pragma unroll
  for (int dt = 0; dt < 4; dt++) {
    #pragma unroll
    for (int j = 0; j < 4; j++) {
      int sq = q0 + g*4 + j;
      float val = cacc[dt][j] / lsum[j];
      ctx[((size_t)(b * S_ + sq)) * D_ + h * DK_ + dt*16 + l15] = f2b(val);
    }
  }
}

// ---------------- LayerNorm over D=1024, one block per row ----------------
__global__ __launch_bounds__(256) void ln_kernel(
    const float* __restrict__ y, const float* __restrict__ gw,
    const float* __restrict__ bw, float* __restrict__ outf,
    u16* __restrict__ outb) {
  int row = blockIdx.x, t = threadIdx.x;
  const float* yr = y + (size_t)row * D_;
  float4 v = reinterpret_cast<const float4*>(yr)[t];
  float s = v.x + v.y + v.z + v.w;
  float ss = v.x*v.x + v.y*v.y + v.z*v.z + v.w*v.w;
  #pragma unroll
  for (int off = 32; off; off >>= 1) {
    s  += __shfl_xor(s, off);
    ss += __shfl_xor(ss, off);
  }
  __shared__ float rsum[4], rsq[4];
  int lane = t & 63, w = t >> 6;
  if (lane == 0) { rsum[w] = s; rsq[w] = ss; }
  __syncthreads();
  s  = rsum[0] + rsum[1] + rsum[2] + rsum[3];
  ss = rsq[0] + rsq[1] + rsq[2] + rsq[3];
  float mu = s * (1.0f / D_);
  float var = ss * (1.0f / D_) - mu * mu;
  float rstd = rsqrtf(var + 1e-5f);
  float4 g4 = reinterpret_cast<const float4*>(gw)[t];
  float4 b4 = reinterpret_cast<const float4*>(bw)[t];
  float4 o;
  o.x = (v.x - mu) * rstd * g4.x + b4.x;
  o.y = (v.y - mu) * rstd * g4.y + b4.y;
  o.z = (v.z - mu) * rstd * g4.z + b4.z;
  o.w = (v.w - mu) * rstd * g4.w + b4.w;
  if (outf) reinterpret_cast<float4*>(outf + (size_t)row * D_)[t] = o;
  if (outb) {
    union { u16 h[4]; uint2 u; } ob;
    ob.h[0] = f2b(o.x); ob.h[1] = f2b(o.y); ob.h[2] = f2b(o.z); ob.h[3] = f2b(o.w);
    reinterpret_cast<uint2*>(outb + (size_t)row * D_)[t] = ob.u;
  }
}

extern "C" void kernel_launch(void* const* d_in, const int* in_sizes, int n_in,
                              void* d_out, int out_size, void* d_ws, size_t ws_size,
                              hipStream_t stream) {
  const float* x     = (const float*)d_in[0];
  const float* Wq    = (const float*)d_in[2];
  const float* Wk    = (const float*)d_in[3];
  const float* Wv    = (const float*)d_in[4];
  const float* W_out = (const float*)d_in[5];
  const float* b_out = (const float*)d_in[6];
  const float* w1    = (const float*)d_in[7];
  const float* b1    = (const float*)d_in[8];
  const float* w2    = (const float*)d_in[9];
  const float* b2    = (const float*)d_in[10];
  const float* ln1g  = (const float*)d_in[11];
  const float* ln1b  = (const float*)d_in[12];
  const float* ln2g  = (const float*)d_in[13];
  const float* ln2b  = (const float*)d_in[14];

  char* ws = (char*)d_ws;
  u16*   WqkvT = (u16*)ws;                         // [0, 6MB)
  u16*   WoutT = (u16*)(ws + (6ll  << 20));        // [6, 8MB)
  u16*   w1T   = (u16*)(ws + (8ll  << 20));        // [8, 16MB)
  u16*   w2T   = (u16*)(ws + (16ll << 20));        // [16, 24MB)
  u16*   xb    = (u16*)(ws + (24ll << 20));        // [24, 32MB)  also x1b
  u16*   qb    = (u16*)(ws + (32ll << 20));        // q,k,v contiguous [32, 56MB)
  u16*   kbuf  = (u16*)(ws + (40ll << 20));
  u16*   vbuf  = (u16*)(ws + (48ll << 20));
  u16*   ctxb  = (u16*)(ws + (56ll << 20));        // [56, 64MB)
  float* y1    = (float*)(ws + (32ll << 20));      // reuse q,k (dead after attn)
  float* x1    = (float*)(ws + (48ll << 20));      // reuse v,ctx (dead after gemm3)
  float* y2    = (float*)(ws + (32ll << 20));      // reuse y1 (dead after ln1)
  u16*   hb    = (u16*)(ws + (64ll << 20));        // [64, 96MB)

  dim3 tb(32, 8);
  // weight transposes -> (N x K) bf16
  transpose_f32_bf16<<<dim3(2, 32, 16), tb, 0, stream>>>(Wq, WqkvT,           1024, 64, 65536, 65536);
  transpose_f32_bf16<<<dim3(2, 32, 16), tb, 0, stream>>>(Wk, WqkvT + 1048576, 1024, 64, 65536, 65536);
  transpose_f32_bf16<<<dim3(2, 32, 16), tb, 0, stream>>>(Wv, WqkvT + 2097152, 1024, 64, 65536, 65536);
  transpose_f32_bf16<<<dim3(32, 32, 1),  tb, 0, stream>>>(W_out, WoutT, 1024, 1024, 0, 0);
  transpose_f32_bf16<<<dim3(128, 32, 1), tb, 0, stream>>>(w1, w1T, 1024, 4096, 0, 0);
  transpose_f32_bf16<<<dim3(32, 128, 1), tb, 0, stream>>>(w2, w2T, 4096, 1024, 0, 0);
  convert_f32_bf16<<<4096, 256, 0, stream>>>(x, xb, B_ * S_ * D_);

  // QKV projection with scatter epilogue
  gemm_bt<0><<<dim3(24, 32), 256, 0, stream>>>(xb, WqkvT, 4096, 3072, 1024,
                                               nullptr, qb, nullptr, nullptr);
  // flash attention
  attn_kernel<<<dim3(32, 32), 256, 0, stream>>>(qb, kbuf, vbuf, ctxb);
  // output projection + bias + residual(inputs) -> y1 (fp32)
  gemm_bt<1><<<dim3(8, 32), 256, 0, stream>>>(ctxb, WoutT, 4096, 1024, 1024,
                                              y1, nullptr, b_out, x);
  // LN1 -> x1 (fp32 residual) + x1b (bf16, into xb slot)
  ln_kernel<<<4096, 256, 0, stream>>>(y1, ln1g, ln1b, x1, xb);
  // FFN1: relu(x1b @ w1 + b1) -> hb (bf16)
  gemm_bt<2><<<dim3(32, 32), 256, 0, stream>>>(xb, w1T, 4096, 4096, 1024,
                                               nullptr, hb, b1, nullptr);
  // FFN2: hb @ w2 + b2 + x1 -> y2 (fp32)
  gemm_bt<1><<<dim3(8, 32), 256, 0, stream>>>(hb, w2T, 4096, 1024, 4096,
                                              y2, nullptr, b2, x1);
  // LN2 -> d_out (fp32)
  ln_kernel<<<4096, 256, 0, stream>>>(y2, ln2g, ln2b, (float*)d_out, nullptr);
}